// Round 6
// baseline (161.404 us; speedup 1.0000x reference)
//
#include <hip/hip_runtime.h>

#define BB 8
#define NN 1024
#define CC 128
#define GG 4
#define LL 8
#define GD 64

typedef __attribute__((ext_vector_type(8))) short short8;
typedef __attribute__((ext_vector_type(4))) float floatx4;

__device__ __forceinline__ short f2b(float f) {
  union { float f; unsigned u; } c; c.f = f;
  unsigned u = c.u;
  return (short)((u + 0x7FFFu + ((u >> 16) & 1u)) >> 16);   // RNE fp32->bf16
}
__device__ __forceinline__ float b2f(short s) {
  union { unsigned u; float f; } c; c.u = ((unsigned)(unsigned short)s) << 16;
  return c.f;
}

// ---------------- Kernel A: projections -> bf16 (V transposed) ----------
// nt 0: q rows [8192][64]; nt 1: k rows; nt 2,3: v cols -> vtb [b][128][1024].
// For nt>=2 the (tm,tn) roles swap so vtb stores are tok-contiguous.
// Stays fp32 vector math: q/k/v rounded only once at output (absmax margin).
__global__ __launch_bounds__(256) void proj_kernel(
    const float* __restrict__ x, const float* __restrict__ Wq,
    const float* __restrict__ Wk, const float* __restrict__ Wv,
    short* __restrict__ qb, short* __restrict__ kb, short* __restrict__ vtb)
{
  __shared__ float xs[32 * 132];
  __shared__ float wsm[64 * 132];
  const int t = threadIdx.x;
  const int m0 = blockIdx.x * 32;
  const int nt = blockIdx.y;

  #pragma unroll
  for (int it = 0; it < 4; ++it) {
    int f = t + it * 256;
    int r = f >> 5, kq = f & 31;
    *(float4*)(xs + r * 132 + kq * 4) = *(const float4*)(x + (m0 + r) * 128 + kq * 4);
  }
  const float* Wsrc = (nt == 0) ? Wq : (nt == 1) ? Wk : (Wv + (nt - 2) * 64 * 128);
  #pragma unroll
  for (int it = 0; it < 8; ++it) {
    int f = t + it * 256;
    int r = f >> 5, kq = f & 31;
    *(float4*)(wsm + r * 132 + kq * 4) = *(const float4*)(Wsrc + r * 128 + kq * 4);
  }
  __syncthreads();

  const int tm = (nt < 2) ? (t >> 4) : (t & 15);
  const int tn = (nt < 2) ? (t & 15) : (t >> 4);
  float acc[2][4] = {};
  for (int kq = 0; kq < 32; ++kq) {
    float4 xa = *(const float4*)(xs + tm * 132 + kq * 4);
    float4 xb = *(const float4*)(xs + (tm + 16) * 132 + kq * 4);
    #pragma unroll
    for (int c = 0; c < 4; ++c) {
      float4 wv = *(const float4*)(wsm + (tn + c * 16) * 132 + kq * 4);
      acc[0][c] += xa.x*wv.x + xa.y*wv.y + xa.z*wv.z + xa.w*wv.w;
      acc[1][c] += xb.x*wv.x + xb.y*wv.y + xb.z*wv.z + xb.w*wv.w;
    }
  }
  #pragma unroll
  for (int a = 0; a < 2; ++a) {
    int row = m0 + tm + a * 16;
    #pragma unroll
    for (int c = 0; c < 4; ++c) {
      short vb = f2b(acc[a][c]);
      int col = tn + c * 16;
      if (nt == 0)      qb[row * 64 + col] = vb;
      else if (nt == 1) kb[row * 64 + col] = vb;
      else {
        int b2 = row >> 10, tok = row & 1023;
        int cv = (nt - 2) * 64 + col;
        vtb[((long)b2 * CC + cv) * NN + tok] = vb;
      }
    }
  }
}

// ---------------- Kernel B: MFMA attention, P stays in registers ----------
// grid 1024: sp = bx&1, itile = (bx>>1)&63, b = bx>>7. 4 waves.
// Per 64-j tile (3 barriers):
//  [A] stage K,V bf16  [B] QK mfma (wave=g) -> arec[i][j*4+g]
//  [C] mix+exp: wave w owns l=2w,2w+1; thread=(i=ln, j-octet=hq); the 8 exps
//      per j-group ARE the PV A-fragment -> PV mfma immediately, no LDS P.
#define IT 16
#define JT 64
#define SPLIT 2
#define JSPAN 512
#define NTL 8
#define KSP 72    // bf16 stride per j-row of ks
#define VTP 72    // bf16 stride per c-row of vt
#define ARP 260   // dword stride per i-row of arec: arec[i][j*4+g]

__global__ __launch_bounds__(256, 3) void attn_kernel(
    const short* __restrict__ qb, const short* __restrict__ kb,
    const short* __restrict__ vtb, const float* __restrict__ masks,
    const float* __restrict__ mask_proj,
    float* __restrict__ pnum, float* __restrict__ pden3)
{
  __shared__ short ks[JT * KSP];     //  9216 B
  __shared__ short vt[CC * VTP];     // 18432 B
  __shared__ float arec[IT * ARP];   // 16640 B   (44288 B -> 3 blocks/CU)

  const int t = threadIdx.x;
  const int sp = blockIdx.x & 1;
  const int itile = (blockIdx.x >> 1) & 63;
  const int b = blockIdx.x >> 7;
  const int i0 = itile * IT;

  const int w = t >> 6;          // wave id: g (QK) ; l-pair owner (mix+PV)
  const int lane = t & 63;
  const int ln = lane & 15;      // i (QK rows via C-layout; mix i; PV m/d)
  const int hq = lane >> 4;      // 0..3
  const int l0 = 2 * w, l1 = 2 * w + 1;

  // Q A-fragment (g = w), K-dim zero-padded 16->32 (hq>=2 lanes zero)
  short8 qf;
  {
    union { short s[8]; short8 v; } qq;
    #pragma unroll
    for (int z = 0; z < 8; ++z) qq.s[z] = 0;
    if (hq < 2)
      qq.v = *(const short8*)(qb + ((long)(b * NN + i0 + ln)) * GD + w * 16 + hq * 8);
    qf = qq.v;
  }
  float ycA[3][4], ycB[3][4];
  #pragma unroll
  for (int m = 0; m < 3; ++m)
    #pragma unroll
    for (int g = 0; g < 4; ++g) {
      ycA[m][g] = mask_proj[m * 32 + g * 8 + l0];
      ycB[m][g] = mask_proj[m * 32 + g * 8 + l1];
    }

  const floatx4 zf = {0.f, 0.f, 0.f, 0.f};
  floatx4 pv0 = zf, pv1 = zf;
  float den0 = 0.f, den1 = 0.f;

  const short* kbase = kb + (long)b * NN * GD;
  const short* vbase = vtb + (long)b * CC * NN;
  const float* mrow = masks + (long)(i0 + ln) * (NN * 3);

  for (int jt = 0; jt < NTL; ++jt) {
    const int j0 = sp * JSPAN + jt * JT;
    __syncthreads();   // A: prior tile's arec/vt readers done

    #pragma unroll
    for (int it2 = 0; it2 < 2; ++it2) {     // stage K: 64 j x 64 d (512 short8)
      int f = t + it2 * 256;
      int j = f >> 3, dg = f & 7;
      short8 v8 = *(const short8*)(kbase + (long)(j0 + j) * GD + dg * 8);
      *(short8*)(ks + j * KSP + dg * 8) = v8;
    }
    #pragma unroll
    for (int it2 = 0; it2 < 4; ++it2) {     // stage V: 128 c x 64 j (1024 short8)
      int f = t + it2 * 256;
      int c = f >> 3, sb = f & 7;
      short8 v8 = *(const short8*)(vbase + (long)c * NN + j0 + sb * 8);
      *(short8*)(vt + c * VTP + sb * 8) = v8;
    }
    __syncthreads();   // B: staged

    // ---- QK: wave g = w; D[i=hq*4+reg][j=ln] -> arec[i][j*4+g] ----
    #pragma unroll
    for (int jsub = 0; jsub < 4; ++jsub) {
      union { short s[8]; short8 v; } kk;
      #pragma unroll
      for (int z = 0; z < 8; ++z) kk.s[z] = 0;
      if (hq < 2)
        kk.v = *(const short8*)(ks + (jsub * 16 + ln) * KSP + w * 16 + hq * 8);
      floatx4 at = __builtin_amdgcn_mfma_f32_16x16x32_bf16(qf, kk.v, zf, 0, 0, 0);
      float* ab = arec + (jsub * 16 + ln) * 4 + w;
      #pragma unroll
      for (int reg = 0; reg < 4; ++reg)
        ab[(hq * 4 + reg) * ARP] = at[reg];
    }
    __syncthreads();   // C: arec ready (ks dead until next stage)

    // ---- mix + exp + PV: thread = (i=ln, j-octet=hq), l = 2w, 2w+1 ----
    #pragma unroll
    for (int mf = 0; mf < 2; ++mf) {
      // masks triples for this thread's 8 j's: 24 floats, float4-aligned
      float mku[24];
      {
        const float* msrc = mrow + (long)(j0 + mf * 32 + hq * 8) * 3;
        #pragma unroll
        for (int q4 = 0; q4 < 6; ++q4)
          *(float4*)(mku + q4 * 4) = *(const float4*)(msrc + q4 * 4);
      }
      union { short s[8]; short8 v; } pA, pB;
      #pragma unroll
      for (int z = 0; z < 8; ++z) {
        floatx4 a4 = *(const floatx4*)(arec + ln * ARP + (mf * 32 + hq * 8 + z) * 4);
        float m0 = mku[z * 3], m1 = mku[z * 3 + 1], m2 = mku[z * 3 + 2];
        float wA0 = m0*ycA[0][0] + m1*ycA[1][0] + m2*ycA[2][0];
        float wA1 = m0*ycA[0][1] + m1*ycA[1][1] + m2*ycA[2][1];
        float wA2 = m0*ycA[0][2] + m1*ycA[1][2] + m2*ycA[2][2];
        float wA3 = m0*ycA[0][3] + m1*ycA[1][3] + m2*ycA[2][3];
        float wB0 = m0*ycB[0][0] + m1*ycB[1][0] + m2*ycB[2][0];
        float wB1 = m0*ycB[0][1] + m1*ycB[1][1] + m2*ycB[2][1];
        float wB2 = m0*ycB[0][2] + m1*ycB[1][2] + m2*ycB[2][2];
        float wB3 = m0*ycB[0][3] + m1*ycB[1][3] + m2*ycB[2][3];
        float scA = a4[0]*wA0 + a4[1]*wA1 + a4[2]*wA2 + a4[3]*wA3;
        float scB = a4[0]*wB0 + a4[1]*wB1 + a4[2]*wB2 + a4[3]*wB3;
        short ea = f2b(__expf(scA));
        short eb = f2b(__expf(scB));
        den0 += b2f(ea);           // denom consistent with bf16 P fed to PV
        den1 += b2f(eb);
        pA.s[z] = ea;
        pB.s[z] = eb;
      }
      short8 vf0 = *(const short8*)(vt + (l0 * 16 + ln) * VTP + mf * 32 + hq * 8);
      pv0 = __builtin_amdgcn_mfma_f32_16x16x32_bf16(pA.v, vf0, pv0, 0, 0, 0);
      short8 vf1 = *(const short8*)(vt + (l1 * 16 + ln) * VTP + mf * 32 + hq * 8);
      pv1 = __builtin_amdgcn_mfma_f32_16x16x32_bf16(pB.v, vf1, pv1, 0, 0, 0);
    }
  }

  // ---- epilogue: partial numerators + per-hq partial denominators ----
  #pragma unroll
  for (int reg = 0; reg < 4; ++reg) {
    long row = ((long)(sp * BB + b)) * NN + i0 + hq * 4 + reg;
    pnum[row * CC + l0 * 16 + ln] = pv0[reg];
    pnum[row * CC + l1 * 16 + ln] = pv1[reg];
  }
  long drow = ((long)(sp * BB + b)) * NN + i0 + ln;
  pden3[drow * 32 + l0 * 4 + hq] = den0;
  pden3[drow * 32 + l1 * 4 + hq] = den1;
}

// ---------------- Kernel C: combine partials ----------------
__global__ __launch_bounds__(256) void reduce_kernel(
    const float* __restrict__ pnum, const float* __restrict__ pden3,
    float* __restrict__ out)
{
  int e4 = blockIdx.x * 256 + threadIdx.x;   // float4 index
  int bi = e4 >> 5;                          // token 0..8191
  int l = (e4 & 31) >> 2;
  const float4* p4 = (const float4*)pnum;
  float4 n0 = p4[e4];
  float4 n1 = p4[e4 + (BB * NN * CC / 4)];
  float den = 0.f;
  #pragma unroll
  for (int s = 0; s < SPLIT; ++s) {
    float4 d4 = *(const float4*)(pden3 + ((long)s * BB * NN + bi) * 32 + l * 4);
    den += d4.x + d4.y + d4.z + d4.w;
  }
  float inv = 1.0f / den;
  float4 o;
  o.x = (n0.x + n1.x) * inv;
  o.y = (n0.y + n1.y) * inv;
  o.z = (n0.z + n1.z) * inv;
  o.w = (n0.w + n1.w) * inv;
  ((float4*)out)[e4] = o;
}

extern "C" void kernel_launch(void* const* d_in, const int* in_sizes, int n_in,
                              void* d_out, int out_size, void* d_ws, size_t ws_size,
                              hipStream_t stream) {
  const float* x         = (const float*)d_in[0];
  const float* masks     = (const float*)d_in[1];
  const float* Wq        = (const float*)d_in[2];
  const float* Wk        = (const float*)d_in[3];
  const float* Wv        = (const float*)d_in[4];
  const float* mask_proj = (const float*)d_in[5];
  float* out = (float*)d_out;

  // ws bytes: qb 1M | kb 1M | vtb 2M | pnum 8M | pden3 2M = 14 MB
  char* wsB = (char*)d_ws;
  short* qb    = (short*)(wsB);
  short* kb    = (short*)(wsB + (1l << 20));
  short* vtb   = (short*)(wsB + (2l << 20));
  float* pnum  = (float*)(wsB + (4l << 20));
  float* pden3 = (float*)(wsB + (12l << 20));

  proj_kernel<<<dim3(256, 4), 256, 0, stream>>>(x, Wq, Wk, Wv, qb, kb, vtb);
  attn_kernel<<<BB * (NN / IT) * SPLIT, 256, 0, stream>>>(qb, kb, vtb, masks,
                                                          mask_proj, pnum, pden3);
  reduce_kernel<<<(BB * NN * CC / 4) / 256, 256, 0, stream>>>(pnum, pden3, out);
}

// Round 7
// 138.419 us; speedup vs baseline: 1.1661x; 1.1661x over previous
//
#include <hip/hip_runtime.h>

#define BB 8
#define NN 1024
#define CC 128
#define GG 4
#define LL 8
#define GD 64

typedef __attribute__((ext_vector_type(8))) short short8;
typedef __attribute__((ext_vector_type(4))) short short4v;
typedef __attribute__((ext_vector_type(4))) float floatx4;

__device__ __forceinline__ short f2b(float f) {
  union { float f; unsigned u; } c; c.f = f;
  unsigned u = c.u;
  return (short)((u + 0x7FFFu + ((u >> 16) & 1u)) >> 16);   // RNE fp32->bf16
}
__device__ __forceinline__ float b2f(short s) {
  union { unsigned u; float f; } c; c.u = ((unsigned)(unsigned short)s) << 16;
  return c.f;
}
__device__ __forceinline__ void split2(float v, short& hi, short& lo) {
  short h = f2b(v);
  hi = h;
  lo = f2b(v - b2f(h));
}

// ---------------- Kernel A: projections via bf16x3 MFMA (no LDS) ----------
// grid 512: nt = bx&3 (0:q, 1:k, 2:v[0:64], 3:v[64:128]), mt = bx>>2 (64-row tile).
// Wave w: rows mt*64+w*16..+15, cols 0..63 of its array. acc = Ah*Bh + Al*Bh + Ah*Bl.
__global__ __launch_bounds__(256) void proj_kernel(
    const float* __restrict__ x, const float* __restrict__ Wq,
    const float* __restrict__ Wk, const float* __restrict__ Wv,
    short* __restrict__ qb, short* __restrict__ kb, short* __restrict__ vtb)
{
  const int t = threadIdx.x;
  const int nt = blockIdx.x & 3;
  const int mt = blockIdx.x >> 2;
  const int w = t >> 6;
  const int lane = t & 63;
  const int ln = lane & 15;
  const int hq = lane >> 4;
  const int arow = mt * 64 + w * 16 + ln;

  const float* wbase = (nt == 0) ? Wq : (nt == 1) ? Wk : (Wv + (nt - 2) * 64 * 128);
  const floatx4 zf = {0.f, 0.f, 0.f, 0.f};
  floatx4 acc[4] = {zf, zf, zf, zf};

  #pragma unroll
  for (int kc = 0; kc < 4; ++kc) {
    const float* xp = x + (long)arow * 128 + kc * 32 + hq * 8;
    float4 a0 = *(const float4*)xp;
    float4 a1 = *(const float4*)(xp + 4);
    union { short s[8]; short8 v; } Ah, Al;
    float av[8] = {a0.x,a0.y,a0.z,a0.w,a1.x,a1.y,a1.z,a1.w};
    #pragma unroll
    for (int z = 0; z < 8; ++z) split2(av[z], Ah.s[z], Al.s[z]);
    #pragma unroll
    for (int ns = 0; ns < 4; ++ns) {
      const float* wp = wbase + (long)(ns * 16 + ln) * 128 + kc * 32 + hq * 8;
      float4 b0 = *(const float4*)wp;
      float4 b1 = *(const float4*)(wp + 4);
      union { short s[8]; short8 v; } Bh, Bl;
      float bv[8] = {b0.x,b0.y,b0.z,b0.w,b1.x,b1.y,b1.z,b1.w};
      #pragma unroll
      for (int z = 0; z < 8; ++z) split2(bv[z], Bh.s[z], Bl.s[z]);
      acc[ns] = __builtin_amdgcn_mfma_f32_16x16x32_bf16(Ah.v, Bh.v, acc[ns], 0,0,0);
      acc[ns] = __builtin_amdgcn_mfma_f32_16x16x32_bf16(Al.v, Bh.v, acc[ns], 0,0,0);
      acc[ns] = __builtin_amdgcn_mfma_f32_16x16x32_bf16(Ah.v, Bl.v, acc[ns], 0,0,0);
    }
  }

  if (nt < 2) {
    short* dst = (nt == 0) ? qb : kb;
    #pragma unroll
    for (int ns = 0; ns < 4; ++ns) {
      int col = ns * 16 + ln;
      #pragma unroll
      for (int reg = 0; reg < 4; ++reg) {
        int row = mt * 64 + w * 16 + hq * 4 + reg;   // C-layout: row=hq*4+reg
        dst[(long)row * 64 + col] = f2b(acc[ns][reg]);
      }
    }
  } else {
    int b = mt >> 4;
    int tok = (mt * 64 + w * 16 + hq * 4) & 1023;    // 4 consecutive tokens/lane
    #pragma unroll
    for (int ns = 0; ns < 4; ++ns) {
      int cv = (nt - 2) * 64 + ns * 16 + ln;
      union { short s[4]; short4v v; } o;
      #pragma unroll
      for (int reg = 0; reg < 4; ++reg) o.s[reg] = f2b(acc[ns][reg]);
      *(short4v*)(vtb + ((long)b * CC + cv) * NN + tok) = o.v;
    }
  }
}

// ---------------- Kernel B: MFMA attention, K/V from global, 2 barriers ----
// grid 2048: sp = bx&3, itile = (bx>>2)&63, b = bx>>8. 4 waves.
// Per 64-j tile: stage masks->mrec[p] | bar1 | QK (global K) -> arec | bar2 |
//                mix+exp (mrec[p], arec) + PV (global V).
#define IT 16
#define JT 64
#define SPLIT 4
#define JSPAN 256
#define NTL 4
#define ARP 260   // dword stride per i-row of arec: arec[i][j*4+g]
#define MRP 196   // dword stride per i-row of mrec: mrec[i][j*3+m]

__global__ __launch_bounds__(256, 3) void attn_kernel(
    const short* __restrict__ qb, const short* __restrict__ kb,
    const short* __restrict__ vtb, const float* __restrict__ masks,
    const float* __restrict__ mask_proj,
    float* __restrict__ pnum, float* __restrict__ pden3)
{
  __shared__ float arec[IT * ARP];       // 16640 B
  __shared__ float mrec[2][IT * MRP];    // 25088 B  (total 41728 -> 3 blocks/CU)

  const int t = threadIdx.x;
  const int sp = blockIdx.x & 3;
  const int itile = (blockIdx.x >> 2) & 63;
  const int b = blockIdx.x >> 8;
  const int i0 = itile * IT;

  const int w = t >> 6;          // wave id: g (QK) ; l-pair owner (mix+PV)
  const int lane = t & 63;
  const int ln = lane & 15;
  const int hq = lane >> 4;
  const int l0 = 2 * w, l1 = 2 * w + 1;

  // Q A-fragment (g = w), K-dim zero-padded 16->32 (hq>=2 lanes zero)
  short8 qf;
  {
    union { short s[8]; short8 v; } qq;
    #pragma unroll
    for (int z = 0; z < 8; ++z) qq.s[z] = 0;
    if (hq < 2)
      qq.v = *(const short8*)(qb + ((long)(b * NN + i0 + ln)) * GD + w * 16 + hq * 8);
    qf = qq.v;
  }
  float ycA[3][4], ycB[3][4];
  #pragma unroll
  for (int m = 0; m < 3; ++m)
    #pragma unroll
    for (int g = 0; g < 4; ++g) {
      ycA[m][g] = mask_proj[m * 32 + g * 8 + l0];
      ycB[m][g] = mask_proj[m * 32 + g * 8 + l1];
    }

  const floatx4 zf = {0.f, 0.f, 0.f, 0.f};
  floatx4 pv0 = zf, pv1 = zf;
  float den0 = 0.f, den1 = 0.f;

  const short* kbase = kb + (long)b * NN * GD;
  const short* v0base = vtb + ((long)b * CC + l0 * 16 + ln) * NN;
  const short* v1base = vtb + ((long)b * CC + l1 * 16 + ln) * NN;

  for (int jt = 0; jt < NTL; ++jt) {
    const int j0 = sp * JSPAN + jt * JT;
    float* mrp = mrec[jt & 1];

    // ---- stage masks 16i x 64j x 3 (768 float4, coalesced) ----
    #pragma unroll
    for (int it2 = 0; it2 < 3; ++it2) {
      int f = t + it2 * 256;
      int ii = f / 48;
      int rem = f - ii * 48;
      *(float4*)(mrp + ii * MRP + rem * 4) =
        *(const float4*)(masks + (long)(i0 + ii) * (NN * 3) + (long)j0 * 3 + rem * 4);
    }
    __syncthreads();   // bar1: mrec[p] staged; prev mix's arec reads done

    // ---- QK: wave g = w, K direct from global ----
    #pragma unroll
    for (int jsub = 0; jsub < 4; ++jsub) {
      union { short s[8]; short8 v; } kk;
      #pragma unroll
      for (int z = 0; z < 8; ++z) kk.s[z] = 0;
      if (hq < 2)
        kk.v = *(const short8*)(kbase + (long)(j0 + jsub * 16 + ln) * GD + w * 16 + hq * 8);
      floatx4 at = __builtin_amdgcn_mfma_f32_16x16x32_bf16(qf, kk.v, zf, 0, 0, 0);
      float* ab = arec + (jsub * 16 + ln) * 4 + w;     // arec[i][j*4+g]
      #pragma unroll
      for (int reg = 0; reg < 4; ++reg)
        ab[(hq * 4 + reg) * ARP] = at[reg];
    }
    __syncthreads();   // bar2: arec ready

    // ---- mix + exp + PV: thread = (i=ln, j-octet=hq), l = 2w, 2w+1 ----
    #pragma unroll
    for (int mf = 0; mf < 2; ++mf) {
      float mku[24];
      {
        const float* mb = mrp + ln * MRP + mf * 96 + hq * 24;
        #pragma unroll
        for (int q4 = 0; q4 < 6; ++q4)
          *(float4*)(mku + q4 * 4) = *(const float4*)(mb + q4 * 4);
      }
      // independent global V loads — issue early
      short8 vf0 = *(const short8*)(v0base + j0 + mf * 32 + hq * 8);
      short8 vf1 = *(const short8*)(v1base + j0 + mf * 32 + hq * 8);
      union { short s[8]; short8 v; } pA, pB;
      #pragma unroll
      for (int z = 0; z < 8; ++z) {
        floatx4 a4 = *(const floatx4*)(arec + ln * ARP + (mf * 32 + hq * 8 + z) * 4);
        float m0 = mku[z * 3], m1 = mku[z * 3 + 1], m2 = mku[z * 3 + 2];
        float wA0 = m0*ycA[0][0] + m1*ycA[1][0] + m2*ycA[2][0];
        float wA1 = m0*ycA[0][1] + m1*ycA[1][1] + m2*ycA[2][1];
        float wA2 = m0*ycA[0][2] + m1*ycA[1][2] + m2*ycA[2][2];
        float wA3 = m0*ycA[0][3] + m1*ycA[1][3] + m2*ycA[2][3];
        float wB0 = m0*ycB[0][0] + m1*ycB[1][0] + m2*ycB[2][0];
        float wB1 = m0*ycB[0][1] + m1*ycB[1][1] + m2*ycB[2][1];
        float wB2 = m0*ycB[0][2] + m1*ycB[1][2] + m2*ycB[2][2];
        float wB3 = m0*ycB[0][3] + m1*ycB[1][3] + m2*ycB[2][3];
        float scA = a4[0]*wA0 + a4[1]*wA1 + a4[2]*wA2 + a4[3]*wA3;
        float scB = a4[0]*wB0 + a4[1]*wB1 + a4[2]*wB2 + a4[3]*wB3;
        short ea = f2b(__expf(scA));
        short eb = f2b(__expf(scB));
        den0 += b2f(ea);           // denom consistent with bf16 P fed to PV
        den1 += b2f(eb);
        pA.s[z] = ea;
        pB.s[z] = eb;
      }
      pv0 = __builtin_amdgcn_mfma_f32_16x16x32_bf16(pA.v, vf0, pv0, 0, 0, 0);
      pv1 = __builtin_amdgcn_mfma_f32_16x16x32_bf16(pB.v, vf1, pv1, 0, 0, 0);
    }
  }

  // ---- epilogue: partial numerators + per-hq partial denominators ----
  #pragma unroll
  for (int reg = 0; reg < 4; ++reg) {
    long row = ((long)(sp * BB + b)) * NN + i0 + hq * 4 + reg;
    pnum[row * CC + l0 * 16 + ln] = pv0[reg];
    pnum[row * CC + l1 * 16 + ln] = pv1[reg];
  }
  long drow = ((long)(sp * BB + b)) * NN + i0 + ln;
  pden3[drow * 32 + l0 * 4 + hq] = den0;
  pden3[drow * 32 + l1 * 4 + hq] = den1;
}

// ---------------- Kernel C: combine partials ----------------
__global__ __launch_bounds__(256) void reduce_kernel(
    const float* __restrict__ pnum, const float* __restrict__ pden3,
    float* __restrict__ out)
{
  int e4 = blockIdx.x * 256 + threadIdx.x;   // float4 index
  int bi = e4 >> 5;                          // token 0..8191
  int l = (e4 & 31) >> 2;
  const float4* p4 = (const float4*)pnum;
  float4 n = {0.f, 0.f, 0.f, 0.f};
  float den = 0.f;
  #pragma unroll
  for (int s = 0; s < SPLIT; ++s) {
    float4 ns = p4[e4 + (long)s * (BB * NN * CC / 4)];
    n.x += ns.x; n.y += ns.y; n.z += ns.z; n.w += ns.w;
    float4 d4 = *(const float4*)(pden3 + ((long)s * BB * NN + bi) * 32 + l * 4);
    den += d4.x + d4.y + d4.z + d4.w;
  }
  float inv = 1.0f / den;
  float4 o;
  o.x = n.x * inv; o.y = n.y * inv; o.z = n.z * inv; o.w = n.w * inv;
  ((float4*)out)[e4] = o;
}

extern "C" void kernel_launch(void* const* d_in, const int* in_sizes, int n_in,
                              void* d_out, int out_size, void* d_ws, size_t ws_size,
                              hipStream_t stream) {
  const float* x         = (const float*)d_in[0];
  const float* masks     = (const float*)d_in[1];
  const float* Wq        = (const float*)d_in[2];
  const float* Wk        = (const float*)d_in[3];
  const float* Wv        = (const float*)d_in[4];
  const float* mask_proj = (const float*)d_in[5];
  float* out = (float*)d_out;

  // ws bytes: qb 1M | kb 1M | vtb 2M | pnum 16M | pden3 4M = 24 MB
  char* wsB = (char*)d_ws;
  short* qb    = (short*)(wsB);
  short* kb    = (short*)(wsB + (1l << 20));
  short* vtb   = (short*)(wsB + (2l << 20));
  float* pnum  = (float*)(wsB + (4l << 20));
  float* pden3 = (float*)(wsB + (20l << 20));

  proj_kernel<<<512, 256, 0, stream>>>(x, Wq, Wk, Wv, qb, kb, vtb);
  attn_kernel<<<BB * (NN / IT) * SPLIT, 256, 0, stream>>>(qb, kb, vtb, masks,
                                                          mask_proj, pnum, pden3);
  reduce_kernel<<<(BB * NN * CC / 4) / 256, 256, 0, stream>>>(pnum, pden3, out);
}